// Round 4
// baseline (491.439 us; speedup 1.0000x reference)
//
#include <hip/hip_runtime.h>

// ---------------------------------------------------------------------------
// RelativeAttention: L=2048, B=2, HID=1024, H=16, DH=64, P=50
//   q,k,v = x @ W^T + b            (bf16 MFMA GEMM, fp32 accumulate)
//   attn  = softmax((QK^T + Sr_gather)/8),  Sr[q,j] = Q[q]·rel_k[j]
//   out_h = attn@V + T@rel_v,      T[q,j] = sum of p over bucket j
//           (middle buckets j in [1,99] hit EXACTLY once -> plain stores)
//   out   = out_h @ Wo^T + bo      (written [L,B,HID])
// R4 attention: barrier-light, global-direct B-frags (L1-served, waves kept
// lockstep with raw s_barrier), per-wave-private LDS (SrS/Tb/Pt) -> 4 blk/CU,
// MFMA epilogue for T@rel_v.  No-max softmax (|scores| <~ 3, validated R2/R3).
// ---------------------------------------------------------------------------

#define LSEQ 2048
#define HIDDIM 1024
#define NH 16
#define DHD 64
#define NREL 101
#define PMAX 50

typedef __attribute__((ext_vector_type(8))) __bf16 bf16x8;
typedef __attribute__((ext_vector_type(4))) float f32x4;

__device__ __forceinline__ unsigned short f2bf(float f) {
  unsigned int u = __builtin_bit_cast(unsigned int, f);
  u += 0x7fffu + ((u >> 16) & 1u);   // RNE
  return (unsigned short)(u >> 16);
}
__device__ __forceinline__ float bflo(unsigned int u) { return __builtin_bit_cast(float, u << 16); }
__device__ __forceinline__ float bfhi(unsigned int u) { return __builtin_bit_cast(float, u & 0xffff0000u); }

__device__ __forceinline__ uint4 pack8(float4 f0, float4 f1) {
  uint4 o;
  o.x = (unsigned)f2bf(f0.x) | ((unsigned)f2bf(f0.y) << 16);
  o.y = (unsigned)f2bf(f0.z) | ((unsigned)f2bf(f0.w) << 16);
  o.z = (unsigned)f2bf(f1.x) | ((unsigned)f2bf(f1.y) << 16);
  o.w = (unsigned)f2bf(f1.z) | ((unsigned)f2bf(f1.w) << 16);
  return o;
}

// fp32 -> bf16 straight cast (weights). 8 elems/thread.
__global__ void cast_w_kernel(const float* __restrict__ src, unsigned short* __restrict__ dst) {
  const int e = (blockIdx.x * 256 + threadIdx.x) * 8;
  const float4 f0 = *(const float4*)(src + e);
  const float4 f1 = *(const float4*)(src + e + 4);
  *(uint4*)(dst + e) = pack8(f0, f1);
}

// [L,B,HID] fp32 -> row m=(b*L+l) bf16 [4096,1024]
__global__ void cast_x_kernel(const float* __restrict__ src, unsigned short* __restrict__ dst) {
  const int e = (blockIdx.x * 256 + threadIdx.x) * 8;
  const int m = e >> 10, k = e & 1023;
  const int b = m >> 11, l = m & 2047;
  const float* s = src + (size_t)((l << 1) + b) * HIDDIM + k;
  const float4 f0 = *(const float4*)s;
  const float4 f1 = *(const float4*)(s + 4);
  *(uint4*)(dst + e) = pack8(f0, f1);
}

// rel_k fp32 [101][64] -> bf16 [112][64], rows 101..111 zeroed
__global__ void cast_rk_kernel(const float* __restrict__ src, unsigned short* __restrict__ dst) {
  const int e = blockIdx.x * 256 + threadIdx.x;
  if (e >= 112 * 64) return;
  dst[e] = (e < NREL * 64) ? f2bf(src[e]) : (unsigned short)0;
}

// rel_v fp32 [101][64] -> transposed bf16 [64][128]: RVb[d][j], j>=101 zero
__global__ void cast_rv_kernel(const float* __restrict__ src, unsigned short* __restrict__ dst) {
  const int e = blockIdx.x * 256 + threadIdx.x;
  if (e >= 64 * 128) return;
  const int d = e >> 7, j = e & 127;
  dst[e] = (j < NREL) ? f2bf(src[j * DHD + d]) : (unsigned short)0;
}

// C[m,n] = sum_k A[m,k]*W[n,k] + bias[n]
// MODE 0: scatter bf16 [B,H,L,DH]; MODE 1: fp32 [L,B,HID]; MODE 2: bf16 V^T [B,H,DH,L]
template <int MODE>
__global__ __launch_bounds__(256, 4) void gemm64(
    const unsigned short* __restrict__ A,   // [4096,1024] bf16
    const unsigned short* __restrict__ W,   // [1024,1024] bf16
    const float* __restrict__ bias,
    float* __restrict__ outF,
    unsigned short* __restrict__ outB) {
  constexpr int K = 1024;
  __shared__ unsigned short As[64 * 72];
  __shared__ unsigned short Bs[64 * 72];
  const int tid = threadIdx.x;
  const int tm = blockIdx.x >> 4, tn = blockIdx.x & 15;
  const int m0 = tm * 64, n0 = tn * 64;
  const int lane = tid & 63, wave = tid >> 6;
  const int wm = (wave >> 1) * 32, wn = (wave & 1) * 32;
  const int qr = lane & 15, quad = lane >> 4;
  const int sr = tid >> 3, sc = (tid & 7) * 8;
  f32x4 acc[2][2] = {};
  for (int k0 = 0; k0 < K; k0 += 64) {
    *(uint4*)&As[sr * 72 + sc]        = *(const uint4*)&A[(size_t)(m0 + sr) * K + k0 + sc];
    *(uint4*)&As[(sr + 32) * 72 + sc] = *(const uint4*)&A[(size_t)(m0 + sr + 32) * K + k0 + sc];
    *(uint4*)&Bs[sr * 72 + sc]        = *(const uint4*)&W[(size_t)(n0 + sr) * K + k0 + sc];
    *(uint4*)&Bs[(sr + 32) * 72 + sc] = *(const uint4*)&W[(size_t)(n0 + sr + 32) * K + k0 + sc];
    __syncthreads();
#pragma unroll
    for (int ks = 0; ks < 64; ks += 32) {
      bf16x8 a0 = *(const bf16x8*)&As[(wm + qr) * 72 + ks + quad * 8];
      bf16x8 a1 = *(const bf16x8*)&As[(wm + 16 + qr) * 72 + ks + quad * 8];
      bf16x8 b0 = *(const bf16x8*)&Bs[(wn + qr) * 72 + ks + quad * 8];
      bf16x8 b1 = *(const bf16x8*)&Bs[(wn + 16 + qr) * 72 + ks + quad * 8];
      acc[0][0] = __builtin_amdgcn_mfma_f32_16x16x32_bf16(a0, b0, acc[0][0], 0, 0, 0);
      acc[0][1] = __builtin_amdgcn_mfma_f32_16x16x32_bf16(a0, b1, acc[0][1], 0, 0, 0);
      acc[1][0] = __builtin_amdgcn_mfma_f32_16x16x32_bf16(a1, b0, acc[1][0], 0, 0, 0);
      acc[1][1] = __builtin_amdgcn_mfma_f32_16x16x32_bf16(a1, b1, acc[1][1], 0, 0, 0);
    }
    __syncthreads();
  }
#pragma unroll
  for (int i = 0; i < 2; i++)
#pragma unroll
    for (int j = 0; j < 2; j++) {
      const int n = n0 + wn + 16 * j + qr;      // C/D: col = lane&15
      const float bv = bias[n];
#pragma unroll
      for (int rr = 0; rr < 4; rr++) {
        const int m = m0 + wm + 16 * i + quad * 4 + rr;  // row = quad*4+reg
        const float v = acc[i][j][rr] + bv;
        const int b = m >> 11, l = m & 2047;
        if (MODE == 0) {
          const int h = n >> 6, d = n & 63;
          outB[((size_t)((b * NH + h) * LSEQ + l) << 6) + d] = f2bf(v);
        } else if (MODE == 1) {
          outF[(size_t)((l << 1) + b) * HIDDIM + n] = v;
        } else {  // V^T: [bh][d][l]
          const int h = n >> 6, d = n & 63;
          outB[(size_t)((b * NH + h) * 64 + d) * LSEQ + l] = f2bf(v);
        }
      }
    }
}

// ---------------------------------------------------------------------------
// Flash-style MFMA attention, global-direct B-frags.
// Block = one (b,h) x 64 q-rows; 4 waves x 16 rows; all LDS wave-private.
// Per-wave LDS (u16 elems): Pt 16x72 @0 | Tb 16x136 @1152 | SrS 16x101 @3328
//   = 4944 -> padded 4952; 4 waves = 39,616 B -> 4 blocks/CU (16 waves/CU).
// ---------------------------------------------------------------------------
#define WREG 4952
__global__ __launch_bounds__(256, 4) void attn_mfma(
    const unsigned short* __restrict__ Qb,   // [32][2048][64] bf16
    const unsigned short* __restrict__ Kb,   // [32][2048][64] bf16
    const unsigned short* __restrict__ Vgt,  // [32][64][2048] bf16 (V^T)
    const unsigned short* __restrict__ RKb,  // [112][64] bf16, zero-padded
    const unsigned short* __restrict__ RVb,  // [64][128] bf16 (rel_v^T), zero-padded
    unsigned short* __restrict__ outB) {     // [B*L][1024] bf16
  __shared__ __align__(16) unsigned short SH[4 * WREG];

  const int tid = threadIdx.x;
  // XCD-aware swizzle: the 32 q-tile blocks of one bh land on one XCD
  const int xcd = blockIdx.x & 7, slot = blockIdx.x >> 3;
  const int bh = (slot >> 5) * 8 + xcd;
  const int q0 = (slot & 31) * 64;

  const int lane = tid & 63, wq = tid >> 6;
  const int c = lane & 15, quad = lane >> 4;
  const size_t base = (size_t)bh * (LSEQ * DHD);
  const unsigned short* Qp = Qb + base;
  const unsigned short* Kp = Kb + base;
  const unsigned short* Vp = Vgt + base;

  unsigned short* Pt  = SH + wq * WREG;          // [16][72]
  unsigned short* Tb  = Pt + 1152;               // [16][136]
  unsigned short* SrS = Pt + 3328;               // [16][101]

  const int qrow_w = q0 + wq * 16;     // wave's first global q (within bh)
  const int srow = quad * 4;           // lane's first wave-local row (+r)

  // zero this wave's Tb (1088 u32)
  for (int e = lane; e < 1088; e += 64) ((unsigned*)Tb)[e] = 0u;

  // Q fragments (A-layout: m=lane&15 -> q row, k=quad*8+j)
  bf16x8 aq0 = *(const bf16x8*)&Qp[(size_t)(qrow_w + c) * DHD + quad * 8];
  bf16x8 aq1 = *(const bf16x8*)&Qp[(size_t)(qrow_w + c) * DHD + 32 + quad * 8];

  // Sr[q][j] = Q[q]·rel_k[j] via MFMA (7 j-tiles of 16), B-frags from global
#pragma unroll
  for (int jt = 0; jt < 7; jt++) {
    bf16x8 b0 = *(const bf16x8*)&RKb[(jt * 16 + c) * DHD + quad * 8];
    bf16x8 b1 = *(const bf16x8*)&RKb[(jt * 16 + c) * DHD + 32 + quad * 8];
    f32x4 s4 = {};
    s4 = __builtin_amdgcn_mfma_f32_16x16x32_bf16(aq0, b0, s4, 0, 0, 0);
    s4 = __builtin_amdgcn_mfma_f32_16x16x32_bf16(aq1, b1, s4, 0, 0, 0);
    const int jc = jt * 16 + c;
    if (jc < NREL) {
#pragma unroll
      for (int r = 0; r < 4; r++) SrS[(srow + r) * NREL + jc] = f2bf(s4[r]);
    }
  }

  float Srlo[4], Srhi[4];
#pragma unroll
  for (int r = 0; r < 4; r++) {
    Srlo[r] = bflo(SrS[(srow + r) * NREL + 0]);
    Srhi[r] = bflo(SrS[(srow + r) * NREL + 100]);
  }

  float rsum[4] = {0.f, 0.f, 0.f, 0.f}, lows[4] = {0.f, 0.f, 0.f, 0.f}, highs[4] = {0.f, 0.f, 0.f, 0.f};
  f32x4 Od[4] = {};

  for (int k0 = 0; k0 < LSEQ; k0 += 64) {
    // wave-uniform band classification: 0=all j==0, 2=all j==100, 1=mixed
    const int mode = (k0 + 63 <= qrow_w - 50) ? 0 : (k0 >= qrow_w + 65) ? 2 : 1;

#pragma unroll
    for (int kt = 0; kt < 4; kt++) {
      const bf16x8 bk0 = *(const bf16x8*)&Kp[(size_t)(k0 + kt * 16 + c) * DHD + quad * 8];
      const bf16x8 bk1 = *(const bf16x8*)&Kp[(size_t)(k0 + kt * 16 + c) * DHD + 32 + quad * 8];
      f32x4 s4 = {};
      s4 = __builtin_amdgcn_mfma_f32_16x16x32_bf16(aq0, bk0, s4, 0, 0, 0);
      s4 = __builtin_amdgcn_mfma_f32_16x16x32_bf16(aq1, bk1, s4, 0, 0, 0);
      const int kcol = k0 + kt * 16 + c;
#pragma unroll
      for (int r = 0; r < 4; r++) {
        float srv;
        int j = 0;
        if (mode == 0) srv = Srlo[r];
        else if (mode == 2) srv = Srhi[r];
        else {
          int dl = kcol - (qrow_w + srow + r);
          dl = dl < -PMAX ? -PMAX : (dl > PMAX ? PMAX : dl);
          j = dl + PMAX;
          srv = bflo(SrS[(srow + r) * NREL + j]);
        }
        const float p = __expf((s4[r] + srv) * 0.125f);
        rsum[r] += p;
        if (mode == 0) lows[r] += p;
        else if (mode == 2) highs[r] += p;
        else {
          if (j == 0) lows[r] += p;
          else if (j == 100) highs[r] += p;
          else Tb[(srow + r) * 136 + j] = f2bf(p);   // exactly-once store
        }
        Pt[(srow + r) * 72 + kt * 16 + c] = f2bf(p);
      }
    }

    // PV: O[16q x 64d] += P[16q x 64k] · V[64k x 64d], B-frags from V^T global
    const bf16x8 ap0 = *(const bf16x8*)&Pt[c * 72 + quad * 8];
    const bf16x8 ap1 = *(const bf16x8*)&Pt[c * 72 + 32 + quad * 8];
#pragma unroll
    for (int t = 0; t < 4; t++) {
      const bf16x8 bv0 = *(const bf16x8*)&Vp[(size_t)(t * 16 + c) * LSEQ + k0 + quad * 8];
      const bf16x8 bv1 = *(const bf16x8*)&Vp[(size_t)(t * 16 + c) * LSEQ + k0 + 32 + quad * 8];
      Od[t] = __builtin_amdgcn_mfma_f32_16x16x32_bf16(ap0, bv0, Od[t], 0, 0, 0);
      Od[t] = __builtin_amdgcn_mfma_f32_16x16x32_bf16(ap1, bv1, Od[t], 0, 0, 0);
    }
    // lockstep-only barrier (no memory drain semantics): keeps the 4 waves'
    // K/V B-frag reads temporally close so L1 serves 3 of 4 waves.
    __builtin_amdgcn_s_barrier();
  }

  // reduce row partials over the 16-lane c-groups
#pragma unroll
  for (int m = 1; m < 16; m <<= 1) {
#pragma unroll
    for (int r = 0; r < 4; r++) {
      rsum[r] += __shfl_xor(rsum[r], m, 64);
      lows[r] += __shfl_xor(lows[r], m, 64);
      highs[r] += __shfl_xor(highs[r], m, 64);
    }
  }
  if (c == 0) {
#pragma unroll
    for (int r = 0; r < 4; r++) {
      Tb[(srow + r) * 136 + 0]   = f2bf(lows[r]);    // bucket 0 never stored in loop
      Tb[(srow + r) * 136 + 100] = f2bf(highs[r]);   // bucket 100 likewise
    }
  }
  __syncthreads();   // make c==0 Tb writes visible to all lanes' A-frag reads

  // w2: O += T @ rel_v via MFMA. A=Tb [16 q][128 j], B=RVb [64 d][128 j].
#pragma unroll
  for (int kc = 0; kc < 4; kc++) {
    const bf16x8 at = *(const bf16x8*)&Tb[c * 136 + kc * 32 + quad * 8];
#pragma unroll
    for (int t = 0; t < 4; t++) {
      const bf16x8 bv = *(const bf16x8*)&RVb[(t * 16 + c) * 128 + kc * 32 + quad * 8];
      Od[t] = __builtin_amdgcn_mfma_f32_16x16x32_bf16(at, bv, Od[t], 0, 0, 0);
    }
  }

  const int b = bh >> 4, h = bh & 15;
#pragma unroll
  for (int r = 0; r < 4; r++) {
    const float inv = 1.f / rsum[r];
    const int qg = q0 + wq * 16 + srow + r;
    unsigned short* op = outB + (size_t)(b * LSEQ + qg) * HIDDIM + h * DHD + c;
#pragma unroll
    for (int t = 0; t < 4; t++) op[t * 16] = f2bf(Od[t][r] * inv);
  }
}

extern "C" void kernel_launch(void* const* d_in, const int* in_sizes, int n_in,
                              void* d_out, int out_size, void* d_ws, size_t ws_size,
                              hipStream_t stream) {
  const float* query = (const float*)d_in[0];
  const float* key   = (const float*)d_in[1];
  const float* value = (const float*)d_in[2];
  const float* Wq = (const float*)d_in[3];  const float* bq = (const float*)d_in[4];
  const float* Wk = (const float*)d_in[5];  const float* bk = (const float*)d_in[6];
  const float* Wv = (const float*)d_in[7];  const float* bv = (const float*)d_in[8];
  const float* Wo = (const float*)d_in[9];  const float* bo = (const float*)d_in[10];
  const float* relk = (const float*)d_in[11];
  const float* relv = (const float*)d_in[12];
  float* out = (float*)d_out;

  // 40 MB workspace layout
  char* w = (char*)d_ws;
  const size_t MB = 1ull << 20;
  unsigned short* Wqb = (unsigned short*)(w + 0 * MB);   // 2MB each
  unsigned short* Wkb = (unsigned short*)(w + 2 * MB);
  unsigned short* Wvb = (unsigned short*)(w + 4 * MB);
  unsigned short* Wob = (unsigned short*)(w + 6 * MB);
  unsigned short* Xb  = (unsigned short*)(w + 8 * MB);   // 8MB staging, reused; also AOb
  unsigned short* Qb  = (unsigned short*)(w + 16 * MB);  // [32][2048][64]
  unsigned short* Kb  = (unsigned short*)(w + 24 * MB);
  unsigned short* Vgt = (unsigned short*)(w + 32 * MB);  // [32][64][2048] (V^T)
  unsigned short* AOb = Xb;
  unsigned short* RKb = Wqb;  // rel_k bf16 [112][64]; Wqb dead after Q-gemm
  unsigned short* RVb = Wkb;  // rel_v^T bf16 [64][128]; Wkb dead after K-gemm

  cast_w_kernel<<<512, 256, 0, stream>>>(Wq, Wqb);
  cast_w_kernel<<<512, 256, 0, stream>>>(Wk, Wkb);
  cast_w_kernel<<<512, 256, 0, stream>>>(Wv, Wvb);
  cast_w_kernel<<<512, 256, 0, stream>>>(Wo, Wob);

  cast_x_kernel<<<2048, 256, 0, stream>>>(query, Xb);
  gemm64<0><<<1024, 256, 0, stream>>>(Xb, Wqb, bq, nullptr, Qb);
  cast_rk_kernel<<<28, 256, 0, stream>>>(relk, RKb);   // after Q-gemm (aliases Wqb)
  cast_x_kernel<<<2048, 256, 0, stream>>>(key, Xb);
  gemm64<0><<<1024, 256, 0, stream>>>(Xb, Wkb, bk, nullptr, Kb);
  cast_rv_kernel<<<32, 256, 0, stream>>>(relv, RVb);   // after K-gemm (aliases Wkb)
  cast_x_kernel<<<2048, 256, 0, stream>>>(value, Xb);
  gemm64<2><<<1024, 256, 0, stream>>>(Xb, Wvb, bv, nullptr, Vgt);

  attn_mfma<<<1024, 256, 0, stream>>>(Qb, Kb, Vgt, RKb, RVb, AOb);

  gemm64<1><<<1024, 256, 0, stream>>>(AOb, Wob, bo, out, nullptr);
}